// Round 9
// baseline (459.360 us; speedup 1.0000x reference)
//
#include <hip/hip_runtime.h>
#include <math.h>

// LoRA-MLP, fp32 in/out. Fold rank-16 LoRA into weights (K=1), then two
// bf16 MFMA GEMMs: h = gelu(x@W1eff^T + b1); out = h@W2eff^T + b2.
// GEMM structure (r9): A-fragments loaded DIRECTLY from global (L2-resident
// by schedule), only B staged through LDS (reg-staged, 2-barrier, BK=64).
#define M_ROWS 12608   // 64*197
#define D_DIM  768
#define H_DIM  3072

typedef __bf16 bf16_t;
typedef __bf16 bf16x8 __attribute__((ext_vector_type(8)));
typedef float  f32x4  __attribute__((ext_vector_type(4)));

// Fast GELU via sigmoid form of tanh approximation (validated r6/r7).
__device__ __forceinline__ float gelu_fast(float v) {
  float v2 = v * v;
  float z = v * fmaf(0.044715f, v2, 1.0f);
  float e = __expf(-1.5957691216057308f * z);
  return v * __builtin_amdgcn_rcpf(1.0f + e);
}

// ---- merged prep: cast x (blocks 0..2363), fold1 (2364..3515), fold2 (..4667)
__device__ __forceinline__ void cast16(const float* __restrict__ in,
                                       bf16_t* __restrict__ out, int blk) {
  long i = ((long)blk * 256 + threadIdx.x) * 16;
  float4 v[4];
#pragma unroll
  for (int q = 0; q < 4; ++q) v[q] = *(const float4*)(in + i + q * 4);
  bf16_t ov[16];
#pragma unroll
  for (int q = 0; q < 4; ++q) {
    ov[q * 4 + 0] = (bf16_t)v[q].x; ov[q * 4 + 1] = (bf16_t)v[q].y;
    ov[q * 4 + 2] = (bf16_t)v[q].z; ov[q * 4 + 3] = (bf16_t)v[q].w;
  }
  *(bf16x8*)(out + i) = *(bf16x8*)ov;
  *(bf16x8*)(out + i + 8) = *(bf16x8*)(ov + 8);
}

__device__ __forceinline__ void fold8(const float* __restrict__ W,
                                      const float* __restrict__ A,
                                      const float* __restrict__ Bm,
                                      bf16_t* __restrict__ Weff,
                                      int IN, int blk) {
  const int nseg = IN >> 3;
  long idx = (long)blk * 256 + threadIdx.x;
  int o = (int)(idx / nseg);
  int s = (int)(idx - (long)o * nseg);
  const float* wp = W + (size_t)o * IN + s * 8;
  float4 w0 = *(const float4*)wp, w1 = *(const float4*)(wp + 4);
  float acc[8] = {w0.x, w0.y, w0.z, w0.w, w1.x, w1.y, w1.z, w1.w};
  float4 b4[4];
#pragma unroll
  for (int q = 0; q < 4; ++q) b4[q] = *(const float4*)(Bm + o * 16 + q * 4);
  const float* bb = (const float*)b4;
#pragma unroll
  for (int r = 0; r < 16; ++r) {
    float b = bb[r];
    const float* ap = A + (size_t)r * IN + s * 8;
    float4 a0 = *(const float4*)ap, a1 = *(const float4*)(ap + 4);
    acc[0] = fmaf(b, a0.x, acc[0]); acc[1] = fmaf(b, a0.y, acc[1]);
    acc[2] = fmaf(b, a0.z, acc[2]); acc[3] = fmaf(b, a0.w, acc[3]);
    acc[4] = fmaf(b, a1.x, acc[4]); acc[5] = fmaf(b, a1.y, acc[5]);
    acc[6] = fmaf(b, a1.z, acc[6]); acc[7] = fmaf(b, a1.w, acc[7]);
  }
  bf16_t ov[8];
#pragma unroll
  for (int i = 0; i < 8; ++i) ov[i] = (bf16_t)acc[i];
  *(bf16x8*)(Weff + (size_t)o * IN + s * 8) = *(bf16x8*)ov;
}

__global__ void prep_kernel(const float* __restrict__ x, bf16_t* __restrict__ xb,
                            const float* __restrict__ W1, const float* __restrict__ A1,
                            const float* __restrict__ B1, bf16_t* __restrict__ W1eff,
                            const float* __restrict__ W2, const float* __restrict__ A2,
                            const float* __restrict__ B2, bf16_t* __restrict__ W2eff) {
  int b = blockIdx.x;
  if (b < 2364) cast16(x, xb, b);                         // 2364*4096 = 9,682,944
  else if (b < 3516) fold8(W1, A1, B1, W1eff, D_DIM, b - 2364);  // 1152 blocks
  else fold8(W2, A2, B2, W2eff, H_DIM, b - 3516);               // 1152 blocks
}

// Unified GEMM: C[m][n] = act(sum_k A[m][k]*B[n][k] + bias[n]).
// 128x128 tile, 4 waves 2x2 (64x64 wave, 4x4 acc of 16x16x32), BK=64.
// A-fragments: direct global bf16x8 loads (lanes m,m+16,m+32,m+48 of a wave
// cover one full 64B line of row m; A-band is L2-resident by schedule).
// B: reg-staged through LDS, XOR-swizzle slot kk^(r&7) (conflict-free),
// 2-barrier K-loop (r7-validated). LDS = B tile only (16KB) -> 3 blocks/CU.
// SCHED 1: per XCD all 24 cols, 13 rbands fast per col -> xb 13-band set
//   (2.5MB) + current W-col (196KB) both L2-resident (r7: FETCH=62MB).
// SCHED 2: 6 cols over two 4-XCD groups, 3 cols fast per rband -> W-cols
//   (2.3MB) resident, hbuf band streamed once.
template <bool GELU, typename OutT, int SCHED, int SMEM_BYTES>
__global__ __launch_bounds__(256, 3) void gemm_kernel(
    const bf16_t* __restrict__ Amat, const bf16_t* __restrict__ Bmat,
    const float* __restrict__ bias, OutT* __restrict__ Cmat,
    int Mrows, int Ncols, int Kd) {
  __shared__ char smem[SMEM_BYTES];
  bf16_t* lds = (bf16_t*)smem;   // B tile [128][64] = 8192 el = 16KB
  float* sT = (float*)smem;      // GELU epilogue scratch [64][132] f32

  int rowb, colb;
  const int xcd = blockIdx.x & 7, t = blockIdx.x >> 3;
  if (SCHED == 1) {              // 24 cols x 13 rbands per XCD, rband-fast
    colb = t / 13;
    rowb = (t % 13) * 8 + xcd;
    if (rowb >= 99) return;
  } else {                       // 3 cols x 25 rbands per XCD, col-fast
    rowb = (t / 3) * 4 + (xcd & 3);
    if (rowb >= 99) return;
    colb = (xcd >> 2) * 3 + (t % 3);
  }
  const int row0 = rowb * 128, col0 = colb * 128;

  const int tid = threadIdx.x, lane = tid & 63, wave = tid >> 6;
  const int wm = wave & 1, wn = wave >> 1;
  const int rl = lane & 15, kc = lane >> 4;

  // A-fragment pointers: frag(mi,ks,it) = 8 bf16 at row row0+wm*64+mi*16+rl,
  // col it*64 + ks*32 + kc*8. Clamp row at M-edge (stores masked later).
  const bf16_t* aP[4];
#pragma unroll
  for (int mi = 0; mi < 4; ++mi) {
    int r = row0 + wm * 64 + mi * 16 + rl;
    if (r > Mrows - 1) r = Mrows - 1;
    aP[mi] = Amat + (size_t)r * Kd + kc * 8;
  }

  // B staging: tile [128 rows][64 k] = 1024 16B-chunks, 4/thread.
  // chunk c -> row c>>3, global k-chunk kkg=c&7, LDS slot kkg^(row&7).
  const bf16_t* gB[4];
  int offB[4];
#pragma unroll
  for (int q = 0; q < 4; ++q) {
    int c = tid + q * 256;
    int r = c >> 3, kkg = c & 7;
    gB[q] = Bmat + (size_t)(col0 + r) * Kd + kkg * 8;
    offB[q] = r * 64 + (kkg ^ (r & 7)) * 8;
  }

  // B fragment offsets for ks=0; ks=1 flips element-offset bit 5 (slot^4).
  int boffs[4];
#pragma unroll
  for (int i = 0; i < 4; ++i) {
    int rb = wn * 64 + i * 16 + rl;
    boffs[i] = rb * 64 + ((kc ^ (rb & 7)) * 8);
  }

  f32x4 acc[4][4] = {};
  f32x4 pB[4];
  const int iters = Kd / 64;

  // prologue: B tile 0 -> regs -> LDS
#pragma unroll
  for (int q = 0; q < 4; ++q) { pB[q] = *(const f32x4*)gB[q]; gB[q] += 64; }
#pragma unroll
  for (int q = 0; q < 4; ++q) *(f32x4*)(lds + offB[q]) = pB[q];
  __syncthreads();

  for (int it = 0; it < iters; ++it) {
    const bool more = (it + 1 < iters);
    if (more) {
#pragma unroll
      for (int q = 0; q < 4; ++q) { pB[q] = *(const f32x4*)gB[q]; gB[q] += 64; }
    }
    // A fragments for this iter: 8 direct global loads (mostly L1/L2 hits)
    bf16x8 af[4][2];
#pragma unroll
    for (int mi = 0; mi < 4; ++mi) {
      af[mi][0] = *(const bf16x8*)(aP[mi]);
      af[mi][1] = *(const bf16x8*)(aP[mi] + 32);
      aP[mi] += 64;
    }
#pragma unroll
    for (int ks = 0; ks < 2; ++ks) {
      bf16x8 bfr[4];
#pragma unroll
      for (int i = 0; i < 4; ++i)
        bfr[i] = *(const bf16x8*)(lds + (boffs[i] ^ (ks * 32)));
#pragma unroll
      for (int mi = 0; mi < 4; ++mi)
#pragma unroll
        for (int ni = 0; ni < 4; ++ni)
          acc[mi][ni] = __builtin_amdgcn_mfma_f32_16x16x32_bf16(
              af[mi][ks], bfr[ni], acc[mi][ni], 0, 0, 0);
    }
    if (more) {
      __syncthreads();                       // all waves done reading B(it)
#pragma unroll
      for (int q = 0; q < 4; ++q)            // vmcnt wait lands here (covered)
        *(f32x4*)(lds + offB[q]) = pB[q];
      __syncthreads();                       // B(it+1) visible
    }
  }

  // epilogue. C/D lane layout: col=lane&15, row=(lane>>4)*4+reg [m89-verified]
  const int crow = (lane >> 4) * 4, ccol = lane & 15;
  if constexpr (GELU) {
    __syncthreads();  // all waves done with LDS before sT reuse
#pragma unroll
    for (int p = 0; p < 2; ++p) {
#pragma unroll
      for (int s = 0; s < 2; ++s) {
        int mi = 2 * p + s;
#pragma unroll
        for (int ni = 0; ni < 4; ++ni)
#pragma unroll
          for (int r = 0; r < 4; ++r)
            sT[(wm * 32 + s * 16 + crow + r) * 132 + wn * 64 + ni * 16 + ccol] =
                acc[mi][ni][r];
      }
      __syncthreads();
      const int erow = tid >> 2, eseg = tid & 3;
      const int grow = row0 + (erow >> 5) * 64 + (2 * p + ((erow >> 4) & 1)) * 16 + (erow & 15);
      if (grow < Mrows) {
        const float* src = sT + erow * 132 + eseg * 32;
        const float* bsrc = bias + col0 + eseg * 32;
        bf16_t ov[32];
#pragma unroll
        for (int i = 0; i < 32; ++i)
          ov[i] = (bf16_t)gelu_fast(src[i] + bsrc[i]);
        bf16_t* dst = (bf16_t*)Cmat + (size_t)grow * Ncols + col0 + eseg * 32;
#pragma unroll
        for (int k = 0; k < 4; ++k)
          *(bf16x8*)(dst + k * 8) = *(bf16x8*)(ov + k * 8);
      }
      __syncthreads();
    }
  } else {
#pragma unroll
    for (int ni = 0; ni < 4; ++ni) {
      const int gc = col0 + wn * 64 + ni * 16 + ccol;
      const float bv = bias[gc];
#pragma unroll
      for (int mi = 0; mi < 4; ++mi) {
        const int gr = row0 + wm * 64 + mi * 16 + crow;
#pragma unroll
        for (int r = 0; r < 4; ++r) {
          const int row = gr + r;
          if (row < Mrows)
            Cmat[(size_t)row * Ncols + gc] = acc[mi][ni][r] + bv;
        }
      }
    }
  }
}

extern "C" void kernel_launch(void* const* d_in, const int* in_sizes, int n_in,
                              void* d_out, int out_size, void* d_ws, size_t ws_size,
                              hipStream_t stream) {
  const float* x  = (const float*)d_in[0];
  const float* W1 = (const float*)d_in[1];
  const float* b1 = (const float*)d_in[2];
  const float* A1 = (const float*)d_in[3];
  const float* B1 = (const float*)d_in[4];
  const float* W2 = (const float*)d_in[5];
  const float* b2 = (const float*)d_in[6];
  const float* A2 = (const float*)d_in[7];
  const float* B2 = (const float*)d_in[8];
  float* out = (float*)d_out;

  char* ws = (char*)d_ws;
  bf16_t* xb    = (bf16_t*)ws;                             // 19,365,888 B (pad)
  bf16_t* W1eff = (bf16_t*)(ws + 19366144);                //  4,718,592 B
  bf16_t* W2eff = (bf16_t*)(ws + 19366144 + 4718592);      //  4,718,592 B
  bf16_t* hbuf  = (bf16_t*)(ws + 19366144 + 2 * 4718592);  // 77,463,552 B

  // merged prep: cast (2364) + fold1 (1152) + fold2 (1152)
  prep_kernel<<<4668, 256, 0, stream>>>(x, xb, W1, A1, B1, W1eff,
                                        W2, A2, B2, W2eff);

  // GEMM1: 99 rbands x 24 cols; per XCD 13 rbands rband-fast -> 24*13*8
  gemm_kernel<true, bf16_t, 1, 33792><<<2496, 256, 0, stream>>>(
      xb, W1eff, b1, hbuf, M_ROWS, H_DIM, D_DIM);
  // GEMM2: 99 rbands x 6 cols; two 4-XCD groups x 3 cols col-fast -> 25*3*8
  gemm_kernel<false, float, 2, 16384><<<600, 256, 0, stream>>>(
      hbuf, W2eff, b2, out, M_ROWS, D_DIM, H_DIM);
}